// Round 2
// baseline (6985.661 us; speedup 1.0000x reference)
//
#include <hip/hip_runtime.h>
#include <hip/hip_bf16.h>
#include <hip/hip_cooperative_groups.h>
#include <cstdint>
#include <cstddef>

namespace cg = cooperative_groups;

#define BATCH  256
#define HID    1024
#define TSTEPS 128
#define NBLK   256
#define NTHR   256

typedef __attribute__((ext_vector_type(8))) short bf16x8;   // 8 bf16 (4 VGPRs)
typedef __attribute__((ext_vector_type(4))) float f32x4;

__device__ inline float bf2f(__hip_bfloat16 h) { return __bfloat162float(h); }

// One-shot prep:
//  - pack w_hh into frag-major hi/lo layout: w_packed[J=64][c=32][f=6][lane=64][8 bf16]
//    f 0..2 = hi parts of gates r,z,n ; f 3..5 = lo parts
//  - split h0 (= vectors) into bf16 hi/lo
//  - prefill out with b_ffn (y partials atomically accumulated on top)
__global__ void prep_kernel(const float* __restrict__ vectors,
                            const float* __restrict__ w_hh,
                            const float* __restrict__ b_ffn,
                            __hip_bfloat16* __restrict__ h_hi0,
                            __hip_bfloat16* __restrict__ h_lo0,
                            __hip_bfloat16* __restrict__ w_packed,
                            float* __restrict__ out)
{
    const long long stride = (long long)gridDim.x * blockDim.x;
    const long long idx = (long long)blockIdx.x * blockDim.x + threadIdx.x;

    const long long NG = 64LL * 32 * 6 * 64;   // 16B groups
    for (long long g = idx; g < NG; g += stride) {
        const int l  = (int)(g & 63);
        long long t1 = g >> 6;
        const int f  = (int)(t1 % 6);
        long long t2 = t1 / 6;
        const int c  = (int)(t2 & 31);
        const int J  = (int)(t2 >> 5);
        const int gate = f % 3, part = f / 3;
        const int row = gate * HID + J * 16 + (l & 15);
        const int col = c * 32 + (l >> 4) * 8;
        const float* src = w_hh + (size_t)row * HID + col;
        alignas(16) __hip_bfloat16 v[8];
        #pragma unroll
        for (int e = 0; e < 8; ++e) {
            float w = src[e];
            __hip_bfloat16 hi = __float2bfloat16(w);
            v[e] = part ? __float2bfloat16(w - bf2f(hi)) : hi;
        }
        *(bf16x8*)(w_packed + g * 8) = *(const bf16x8*)v;
    }

    const long long NH = (long long)BATCH * HID;
    for (long long i = idx; i < NH; i += stride) {
        float h = vectors[i];
        __hip_bfloat16 hi = __float2bfloat16(h);
        h_hi0[i] = hi;
        h_lo0[i] = __float2bfloat16(h - bf2f(hi));
    }
    const float bf = b_ffn[0];
    for (long long i = idx; i < (long long)BATCH * TSTEPS; i += stride) out[i] = bf;
}

// Persistent GRU: all 128 steps in one cooperative kernel.
// Grid 256 blocks (1/CU) x 256 thr (4 waves).
// Block = (m_tile 0..3: 64 batch rows) x (j_tile 0..63: 16 h-cols, 3 gates).
// j-tiles grouped per XCD (blk&7) so each XCD's B slice (1.57 MB) stays L2-hot.
// Wave w = 16 batch rows. h master lives in registers (4 floats/thread).
__global__ __launch_bounds__(NTHR)
void gru_persistent(const float* __restrict__ vectors,
                    const float* __restrict__ w_ih,
                    const float* __restrict__ b_ih,
                    const float* __restrict__ b_hh,
                    const float* __restrict__ w_ffn,
                    const float* __restrict__ first_input,
                    __hip_bfloat16* __restrict__ h_hi_a,
                    __hip_bfloat16* __restrict__ h_lo_a,
                    __hip_bfloat16* __restrict__ h_hi_b,
                    __hip_bfloat16* __restrict__ h_lo_b,
                    const __hip_bfloat16* __restrict__ w_packed,
                    float* __restrict__ out)
{
    cg::grid_group grid = cg::this_grid();

    const int blk = blockIdx.x;
    const int xcd = blk & 7;
    const int ii  = blk >> 3;          // 0..31
    const int j_tile = xcd * 8 + (ii & 7);   // 0..63, same-j group on same XCD
    const int m_tile = ii >> 3;              // 0..3
    const int wave = threadIdx.x >> 6;
    const int lane = threadIdx.x & 63;
    const int l15  = lane & 15;
    const int kg   = lane >> 4;
    const int m_sub = m_tile * 64 + wave * 16;
    const int j = j_tile * 16 + l15;

    // per-thread step-invariant scalars
    const float bhr = b_hh[j], bhz = b_hh[HID + j], bhn = b_hh[2 * HID + j];
    const float wir = w_ih[j], wiz = w_ih[HID + j], win = w_ih[2 * HID + j];
    const float bir = b_ih[j], biz = b_ih[HID + j], bin_ = b_ih[2 * HID + j];
    const float wf = w_ffn[j];
    const float x0 = first_input[0];

    // fp32 h master in registers: rows m_sub+kg*4+r, col j — only this thread touches them
    float hreg[4];
    #pragma unroll
    for (int r = 0; r < 4; ++r)
        hreg[r] = vectors[(size_t)(m_sub + kg * 4 + r) * HID + j];

    // A-frag base offset (per lane): row = m_sub + l15, k-base = kg*8
    const size_t aoff = (size_t)(m_sub + l15) * HID + kg * 8;
    // B frags: packed, contiguous 16B per lane, identical addrs across the 4 waves
    const bf16x8* __restrict__ Bbase =
        (const bf16x8*)(w_packed + (size_t)j_tile * 32 * 6 * 64 * 8 + (size_t)lane * 8);

    for (int t = 0; t < TSTEPS; ++t) {
        const __hip_bfloat16* __restrict__ hhi = (t & 1) ? h_hi_b : h_hi_a;
        const __hip_bfloat16* __restrict__ hlo = (t & 1) ? h_lo_b : h_lo_a;
        __hip_bfloat16* __restrict__ nhi = (t & 1) ? h_hi_a : h_hi_b;
        __hip_bfloat16* __restrict__ nlo = (t & 1) ? h_lo_a : h_lo_b;

        const bf16x8* __restrict__ pAhi = (const bf16x8*)(hhi + aoff);
        const bf16x8* __restrict__ pAlo = (const bf16x8*)(hlo + aoff);

        f32x4 acc0 = {0.f, 0.f, 0.f, 0.f};
        f32x4 acc1 = acc0, acc2 = acc0;

        #pragma unroll 2
        for (int c = 0; c < 32; ++c) {
            const bf16x8* __restrict__ pB = Bbase + (size_t)c * 384;  // c*3072 elems /8
            bf16x8 ahi = pAhi[c * 4];
            bf16x8 alo = pAlo[c * 4];
            bf16x8 bhi0 = pB[0];
            bf16x8 bhi1 = pB[64];
            bf16x8 bhi2 = pB[128];
            bf16x8 blo0 = pB[192];
            bf16x8 blo1 = pB[256];
            bf16x8 blo2 = pB[320];
            acc0 = __builtin_amdgcn_mfma_f32_16x16x32_bf16(ahi, bhi0, acc0, 0, 0, 0);
            acc1 = __builtin_amdgcn_mfma_f32_16x16x32_bf16(ahi, bhi1, acc1, 0, 0, 0);
            acc2 = __builtin_amdgcn_mfma_f32_16x16x32_bf16(ahi, bhi2, acc2, 0, 0, 0);
            acc0 = __builtin_amdgcn_mfma_f32_16x16x32_bf16(ahi, blo0, acc0, 0, 0, 0);
            acc1 = __builtin_amdgcn_mfma_f32_16x16x32_bf16(ahi, blo1, acc1, 0, 0, 0);
            acc2 = __builtin_amdgcn_mfma_f32_16x16x32_bf16(ahi, blo2, acc2, 0, 0, 0);
            acc0 = __builtin_amdgcn_mfma_f32_16x16x32_bf16(alo, bhi0, acc0, 0, 0, 0);
            acc1 = __builtin_amdgcn_mfma_f32_16x16x32_bf16(alo, bhi1, acc1, 0, 0, 0);
            acc2 = __builtin_amdgcn_mfma_f32_16x16x32_bf16(alo, bhi2, acc2, 0, 0, 0);
        }

        // Epilogue: C/D layout col=lane&15, row=(lane>>4)*4+r
        #pragma unroll
        for (int r = 0; r < 4; ++r) {
            const int brow = m_sub + kg * 4 + r;
            const float x = (t == 0) ? x0 : out[(size_t)brow * TSTEPS + (t - 1)];
            const float ghr = acc0[r] + bhr;
            const float ghz = acc1[r] + bhz;
            const float ghn = acc2[r] + bhn;
            const float gir = fmaf(x, wir, bir);
            const float giz = fmaf(x, wiz, biz);
            const float gin = fmaf(x, win, bin_);
            const float rg = 1.f / (1.f + expf(-(gir + ghr)));
            const float zg = 1.f / (1.f + expf(-(giz + ghz)));
            const float ng = tanhf(fmaf(rg, ghn, gin));
            const float hnew = (1.f - zg) * ng + zg * hreg[r];
            hreg[r] = hnew;
            const __hip_bfloat16 hi = __float2bfloat16(hnew);
            nhi[(size_t)brow * HID + j] = hi;
            nlo[(size_t)brow * HID + j] = __float2bfloat16(hnew - bf2f(hi));
            float py = hnew * wf;
            py += __shfl_xor(py, 1);
            py += __shfl_xor(py, 2);
            py += __shfl_xor(py, 4);
            py += __shfl_xor(py, 8);
            if (l15 == 0) atomicAdd(&out[(size_t)brow * TSTEPS + t], py);
        }

        grid.sync();
    }
}

extern "C" void kernel_launch(void* const* d_in, const int* in_sizes, int n_in,
                              void* d_out, int out_size, void* d_ws, size_t ws_size,
                              hipStream_t stream)
{
    const float* vectors     = (const float*)d_in[0];
    const float* w_ih        = (const float*)d_in[1];
    const float* w_hh        = (const float*)d_in[2];
    const float* b_ih        = (const float*)d_in[3];
    const float* b_hh        = (const float*)d_in[4];
    const float* w_ffn       = (const float*)d_in[5];
    const float* b_ffn       = (const float*)d_in[6];
    const float* first_input = (const float*)d_in[7];
    float* out = (float*)d_out;

    // workspace carve (~14.7 MB)
    char* p = (char*)d_ws;
    __hip_bfloat16* h_hi_a = (__hip_bfloat16*)p;  p += (size_t)BATCH * HID * 2;
    __hip_bfloat16* h_lo_a = (__hip_bfloat16*)p;  p += (size_t)BATCH * HID * 2;
    __hip_bfloat16* h_hi_b = (__hip_bfloat16*)p;  p += (size_t)BATCH * HID * 2;
    __hip_bfloat16* h_lo_b = (__hip_bfloat16*)p;  p += (size_t)BATCH * HID * 2;
    __hip_bfloat16* w_packed = (__hip_bfloat16*)p; p += 64LL * 32 * 6 * 64 * 8 * 2;

    prep_kernel<<<512, 256, 0, stream>>>(vectors, w_hh, b_ffn,
                                         h_hi_a, h_lo_a, w_packed, out);

    void* args[] = {
        (void*)&vectors, (void*)&w_ih, (void*)&b_ih, (void*)&b_hh,
        (void*)&w_ffn, (void*)&first_input,
        (void*)&h_hi_a, (void*)&h_lo_a, (void*)&h_hi_b, (void*)&h_lo_b,
        (void*)&w_packed, (void*)&out
    };
    hipLaunchCooperativeKernel((const void*)gru_persistent,
                               dim3(NBLK), dim3(NTHR), args, 0, stream);
}

// Round 3
// 2138.562 us; speedup vs baseline: 3.2665x; 3.2665x over previous
//
#include <hip/hip_runtime.h>
#include <hip/hip_bf16.h>
#include <cstdint>
#include <cstddef>

#define BATCH  256
#define HID    1024
#define TSTEPS 128
#define NBLK   256
#define NTHR   768   // 12 waves: (n-tile 0..5) x (m-tile 0..1)

typedef __attribute__((ext_vector_type(8))) short bf16x8;
typedef __attribute__((ext_vector_type(4))) float f32x4;

__device__ inline float bf2f(__hip_bfloat16 h) { return __bfloat162float(h); }

// ---------------------------------------------------------------------------
// prep: pack w_hh (hi+lo split) into frag-major layout, h0 -> bf16, prefill
// out with b_ffn, zero barrier counters.
// w2 chunk g (16B): decode -> jb(0..31), n(0..5: gate=n>>1, colhalf=n&1),
//   c(0..31), part(0=hi,1=lo), l(0..63).
//   wrow = gate*1024 + jb*32 + ch*16 + (l&15); k = c*32 + (l>>4)*8
// ---------------------------------------------------------------------------
__global__ void prep_kernel(const float* __restrict__ vectors,
                            const float* __restrict__ w_hh,
                            const float* __restrict__ b_ffn,
                            __hip_bfloat16* __restrict__ h0,
                            __hip_bfloat16* __restrict__ w2,
                            unsigned* __restrict__ bar,
                            float* __restrict__ out)
{
    const long long stride = (long long)gridDim.x * blockDim.x;
    const long long idx = (long long)blockIdx.x * blockDim.x + threadIdx.x;

    const long long NG = 32LL * 6 * 32 * 2 * 64;   // 786432 chunks
    for (long long g = idx; g < NG; g += stride) {
        const int l    = (int)(g & 63);
        const int part = (int)((g >> 6) & 1);
        const int c    = (int)((g >> 7) & 31);
        const int nj   = (int)(g >> 12);
        const int n    = nj % 6;
        const int jb   = nj / 6;
        const int gate = n >> 1, ch = n & 1;
        const int wrow = gate * HID + jb * 32 + ch * 16 + (l & 15);
        const int k    = c * 32 + (l >> 4) * 8;
        const float* src = w_hh + (size_t)wrow * HID + k;
        alignas(16) __hip_bfloat16 v[8];
        #pragma unroll
        for (int e = 0; e < 8; ++e) {
            float w = src[e];
            __hip_bfloat16 hi = __float2bfloat16(w);
            v[e] = part ? __float2bfloat16(w - bf2f(hi)) : hi;
        }
        *(bf16x8*)(w2 + g * 8) = *(const bf16x8*)v;
    }

    const long long NH = (long long)BATCH * HID;
    for (long long i = idx; i < NH; i += stride)
        h0[i] = __float2bfloat16(vectors[i]);

    const float bf = b_ffn[0];
    for (long long i = idx; i < (long long)BATCH * TSTEPS; i += stride) out[i] = bf;

    for (long long i = idx; i < TSTEPS * 16 + TSTEPS; i += stride) bar[i] = 0u;
}

// ---------------------------------------------------------------------------
// Persistent GRU. Block: jblk (32 cols -> 96 w-rows), mgrp (32 batch rows).
// Same-jblk blocks share an XCD (blk&7) -> 1.57 MB weights/XCD stay L2-hot.
// h/x cross-block traffic via SYSTEM-scope atomics (IC-coherent, no cache
// maintenance). Custom 2-level barrier per step. h master in registers.
// ---------------------------------------------------------------------------
__global__ __launch_bounds__(NTHR)
void gru_persistent(const float* __restrict__ vectors,
                    const float* __restrict__ w_ih,
                    const float* __restrict__ b_ih,
                    const float* __restrict__ b_hh,
                    const float* __restrict__ w_ffn,
                    const float* __restrict__ first_input,
                    __hip_bfloat16* __restrict__ h_a,
                    __hip_bfloat16* __restrict__ h_b,
                    const __hip_bfloat16* __restrict__ w2,
                    unsigned* __restrict__ bar,
                    float* __restrict__ out)
{
    __shared__ uint4 ldsA[4096];          // 64 KB: A frags, swizzled
    __shared__ float gh[3][32][32];       // 12 KB
    __shared__ float x_lds[32];

    const int blk  = blockIdx.x;
    const int xcd  = blk & 7, q = blk >> 3;
    const int jblk = xcd * 4 + (q & 3);   // 0..31, co-located per XCD
    const int mgrp = q >> 2;              // 0..7
    const int m_base = mgrp * 32, j_base = jblk * 32;
    const int tid  = threadIdx.x;
    const int wv   = tid >> 6, lane = tid & 63;
    const int n    = wv >> 1, mt = wv & 1;
    const int gate = n >> 1, ch = n & 1;

    // epilogue ownership: elems i = tid, tid+768 of 32b x 32jc grid
    float wih_[2][3], bih_[2][3], bhh_[2][3], wf_[2], hreg[2];
    #pragma unroll
    for (int k = 0; k < 2; ++k) {
        int i = tid + k * NTHR;
        if (i < 1024) {
            int b = i >> 5, jc = i & 31;
            int j = j_base + jc, brow = m_base + b;
            #pragma unroll
            for (int g = 0; g < 3; ++g) {
                wih_[k][g] = w_ih[g * HID + j];
                bih_[k][g] = b_ih[g * HID + j];
                bhh_[k][g] = b_hh[g * HID + j];
            }
            wf_[k] = w_ffn[j];
            hreg[k] = vectors[(size_t)brow * HID + j];
        }
    }
    const float x0 = first_input[0];
    unsigned* leaf = bar;
    unsigned* root = bar + TSTEPS * 16;

    const bf16x8* __restrict__ Bb =
        (const bf16x8*)w2 + ((size_t)jblk * 6 + n) * 4096;  // 4096 frags/(jb,n)

    for (int t = 0; t < TSTEPS; ++t) {
        const __hip_bfloat16* hcur = (t & 1) ? h_b : h_a;
        __hip_bfloat16* hnxt = (t & 1) ? h_a : h_b;

        // ---- phase 0: x + A-stage into LDS (frag-major, XOR-swizzled) ----
        if (tid < 32) {
            float xv = x0;
            if (t > 0)
                xv = __hip_atomic_load(&out[(size_t)(m_base + tid) * TSTEPS + t - 1],
                                       __ATOMIC_RELAXED, __HIP_MEMORY_SCOPE_SYSTEM);
            x_lds[tid] = xv;
        }
        const unsigned* hsrc32 = (const unsigned*)hcur + (size_t)m_base * 512;
        for (int g = tid; g < 16384; g += NTHR) {
            int row = g >> 9, cp = g & 511;       // row 0..31, cp = k/2
            unsigned v = __hip_atomic_load(&hsrc32[(size_t)row * 512 + cp],
                                           __ATOMIC_RELAXED, __HIP_MEMORY_SCOPE_SYSTEM);
            int mtw = row >> 4, rr = row & 15;
            int c = cp >> 4, ls = rr + ((cp >> 2) & 3) * 16;
            int slot = (mtw * 32 + c) * 64 + (ls ^ (c & 7));
            ((unsigned*)&ldsA[slot])[cp & 3] = v;
        }
        __syncthreads();

        // ---- compute: wave (n, mt): 32 c-steps x 2 products ----
        f32x4 acc = {0.f, 0.f, 0.f, 0.f};
        #pragma unroll 4
        for (int c = 0; c < 32; ++c) {
            bf16x8 a  = *(const bf16x8*)&ldsA[(mt * 32 + c) * 64 + (lane ^ (c & 7))];
            bf16x8 bh = Bb[(c * 2) * 64 + lane];
            bf16x8 bl = Bb[(c * 2 + 1) * 64 + lane];
            acc = __builtin_amdgcn_mfma_f32_16x16x32_bf16(a, bh, acc, 0, 0, 0);
            acc = __builtin_amdgcn_mfma_f32_16x16x32_bf16(a, bl, acc, 0, 0, 0);
        }
        {
            int jc = ch * 16 + (lane & 15);
            int rowb = mt * 16 + (lane >> 4) * 4;
            #pragma unroll
            for (int r = 0; r < 4; ++r) gh[gate][rowb + r][jc] = acc[r];
        }
        __syncthreads();

        // ---- epilogue: gates, h update, h-hi store, y reduce ----
        #pragma unroll
        for (int k = 0; k < 2; ++k) {
            int i = tid + k * NTHR;
            bool own = i < 1024;
            unsigned hbits = 0; int brow = 0, jc = 0; float py = 0.f;
            if (own) {
                int b = i >> 5; jc = i & 31; brow = m_base + b;
                float x = x_lds[b];
                float ghr = gh[0][b][jc] + bhh_[k][0];
                float ghz = gh[1][b][jc] + bhh_[k][1];
                float ghn = gh[2][b][jc] + bhh_[k][2];
                float gir = fmaf(x, wih_[k][0], bih_[k][0]);
                float giz = fmaf(x, wih_[k][1], bih_[k][1]);
                float gin = fmaf(x, wih_[k][2], bih_[k][2]);
                float rg = 1.f / (1.f + expf(-(gir + ghr)));
                float zg = 1.f / (1.f + expf(-(giz + ghz)));
                float ng = tanhf(fmaf(rg, ghn, gin));
                float hnew = (1.f - zg) * ng + zg * hreg[k];
                hreg[k] = hnew;
                __hip_bfloat16 hb = __float2bfloat16(hnew);
                hbits = (unsigned)__builtin_bit_cast(unsigned short, hb);
                py = hnew * wf_[k];
            }
            unsigned other = (unsigned)__shfl_xor((int)hbits, 1);
            if (own && ((tid & 1) == 0)) {
                unsigned val = (hbits & 0xffffu) | (other << 16);
                __hip_atomic_store((unsigned*)hnxt + (size_t)brow * 512 + ((j_base + jc) >> 1),
                                   val, __ATOMIC_RELAXED, __HIP_MEMORY_SCOPE_SYSTEM);
            }
            py += __shfl_xor(py, 1);
            py += __shfl_xor(py, 2);
            py += __shfl_xor(py, 4);
            py += __shfl_xor(py, 8);
            py += __shfl_xor(py, 16);
            if (own && ((tid & 31) == 0))
                __hip_atomic_fetch_add(&out[(size_t)brow * TSTEPS + t], py,
                                       __ATOMIC_RELAXED, __HIP_MEMORY_SCOPE_SYSTEM);
        }

        // ---- grid barrier (2-level, fresh counters per step) ----
        if (t != TSTEPS - 1) {
            __syncthreads();   // drains each wave's vmcnt before arrive
            if (tid == 0) {
                if (__hip_atomic_fetch_add(&leaf[t * 16 + (blk & 15)], 1u,
                        __ATOMIC_RELAXED, __HIP_MEMORY_SCOPE_SYSTEM) == 15u)
                    __hip_atomic_fetch_add(&root[t], 1u,
                        __ATOMIC_RELAXED, __HIP_MEMORY_SCOPE_SYSTEM);
                while (__hip_atomic_load(&root[t], __ATOMIC_RELAXED,
                                         __HIP_MEMORY_SCOPE_SYSTEM) != 16u)
                    __builtin_amdgcn_s_sleep(8);
            }
            __syncthreads();
        }
    }
}

extern "C" void kernel_launch(void* const* d_in, const int* in_sizes, int n_in,
                              void* d_out, int out_size, void* d_ws, size_t ws_size,
                              hipStream_t stream)
{
    const float* vectors     = (const float*)d_in[0];
    const float* w_ih        = (const float*)d_in[1];
    const float* w_hh        = (const float*)d_in[2];
    const float* b_ih        = (const float*)d_in[3];
    const float* b_hh        = (const float*)d_in[4];
    const float* w_ffn       = (const float*)d_in[5];
    const float* b_ffn       = (const float*)d_in[6];
    const float* first_input = (const float*)d_in[7];
    float* out = (float*)d_out;

    // workspace carve (~13.6 MB)
    char* p = (char*)d_ws;
    __hip_bfloat16* h_a = (__hip_bfloat16*)p;  p += (size_t)BATCH * HID * 2;
    __hip_bfloat16* h_b = (__hip_bfloat16*)p;  p += (size_t)BATCH * HID * 2;
    __hip_bfloat16* w2  = (__hip_bfloat16*)p;  p += 32LL * 6 * 32 * 2 * 64 * 8 * 2;
    unsigned* bar = (unsigned*)p;              p += (TSTEPS * 16 + TSTEPS) * 4;

    prep_kernel<<<1024, 256, 0, stream>>>(vectors, w_hh, b_ffn, h_a, w2, bar, out);

    void* args[] = {
        (void*)&vectors, (void*)&w_ih, (void*)&b_ih, (void*)&b_hh,
        (void*)&w_ffn, (void*)&first_input,
        (void*)&h_a, (void*)&h_b, (void*)&w2, (void*)&bar, (void*)&out
    };
    hipLaunchCooperativeKernel((const void*)gru_persistent,
                               dim3(NBLK), dim3(NTHR), args, 0, stream);
}